// Round 9
// baseline (273.718 us; speedup 1.0000x reference)
//
#include <hip/hip_runtime.h>
#include <hip/hip_bf16.h>

#define NN 50000      // nodes
#define MP 50176      // padded nodes (392 * 128)
#define NF 64         // features
#define NH 512        // hidden
#define NE 800000     // edges
#define NB 196        // scan blocks = ceil(NN/256)
#define MB 392        // M blocks = MP/128
#define GRID (MB * 4) // 1568 = 8 * 196
#define CPX (GRID / 8)

typedef __attribute__((ext_vector_type(8))) short bf16x8;
typedef __attribute__((ext_vector_type(4))) float f32x4;

#define GLOAD16(g, l)                                                        \
    __builtin_amdgcn_global_load_lds(                                        \
        (const __attribute__((address_space(1))) unsigned int*)(g),          \
        (__attribute__((address_space(3))) unsigned int*)(l), 16, 0, 0)

// ---------------------------------------------------------------------------
// detect whether edge_index is int64 (high dwords all zero) or int32
__global__ void detect_idx(const int* __restrict__ ei, int* __restrict__ flag) {
    if (threadIdx.x == 0 && blockIdx.x == 0) {
        int any = 0;
        for (int i = 0; i < 32; ++i) any |= ei[2 * i + 1];
        *flag = (any == 0) ? 1 : 0;   // 1 => int64 layout
    }
}

// ---------------------------------------------------------------------------
// CSR build: histogram of dst
__global__ __launch_bounds__(256) void edge_hist(const void* __restrict__ eiv,
                                                 const int* __restrict__ flag,
                                                 int* __restrict__ deg) {
    int e = blockIdx.x * 256 + threadIdx.x;
    if (e >= NE) return;
    int dst = *flag ? (int)((const long long*)eiv)[NE + e]
                    : ((const int*)eiv)[NE + e];
    atomicAdd(&deg[dst], 1);
}

// parallel scan step 1: per-block exclusive prefix + block sums
__global__ __launch_bounds__(256) void scan_local(const int* __restrict__ deg,
                                                  int* __restrict__ rowptr,
                                                  int* __restrict__ bsum) {
    __shared__ int sm[256];
    int tid = threadIdx.x;
    int i = blockIdx.x * 256 + tid;
    int v = (i < NN) ? deg[i] : 0;
    sm[tid] = v;
    __syncthreads();
    int acc = v;
#pragma unroll
    for (int off = 1; off < 256; off <<= 1) {
        int t = (tid >= off) ? sm[tid - off] : 0;
        __syncthreads();
        acc += t;
        sm[tid] = acc;
        __syncthreads();
    }
    if (i < NN) rowptr[i] = acc - v;           // local exclusive
    if (tid == 255) bsum[blockIdx.x] = acc;    // block total
}

// parallel scan step 2: exclusive scan of the NB block sums (1 block)
__global__ __launch_bounds__(256) void scan_bsum(const int* __restrict__ bsum,
                                                 int* __restrict__ boff) {
    __shared__ int sm[256];
    int tid = threadIdx.x;
    int v = (tid < NB) ? bsum[tid] : 0;
    sm[tid] = v;
    __syncthreads();
    int acc = v;
#pragma unroll
    for (int off = 1; off < 256; off <<= 1) {
        int t = (tid >= off) ? sm[tid - off] : 0;
        __syncthreads();
        acc += t;
        sm[tid] = acc;
        __syncthreads();
    }
    if (tid < NB) boff[tid] = acc - v;         // exclusive
}

// parallel scan step 3: add block offsets, emit rowptr & cursor
__global__ __launch_bounds__(256) void scan_add(int* __restrict__ rowptr,
                                                const int* __restrict__ boff,
                                                int* __restrict__ cursor) {
    int i = blockIdx.x * 256 + threadIdx.x;
    if (i < NN) {
        int r = rowptr[i] + boff[blockIdx.x];
        rowptr[i] = r;
        cursor[i] = r;
    }
    if (i == 0) rowptr[NN] = NE;   // total is the edge count by construction
}

// scatter edge sources into CSR slots
__global__ __launch_bounds__(256) void edge_fill(const void* __restrict__ eiv,
                                                 const int* __restrict__ flag,
                                                 int* __restrict__ cursor,
                                                 int* __restrict__ csr) {
    int e = blockIdx.x * 256 + threadIdx.x;
    if (e >= NE) return;
    int src, dst;
    if (*flag) {
        const long long* ei = (const long long*)eiv;
        src = (int)ei[e];
        dst = (int)ei[NE + e];
    } else {
        const int* ei = (const int*)eiv;
        src = ei[e];
        dst = ei[NE + e];
    }
    int pos = atomicAdd(&cursor[dst], 1);
    csr[pos] = src;
}

// gather-sum: h0b[n] = bf16( x[n] + sum_{s in N(n)} x[s] ), padded rows zero.
__global__ __launch_bounds__(256) void gather(const float* __restrict__ x,
                                              const int* __restrict__ rowptr,
                                              const int* __restrict__ csr,
                                              __hip_bfloat16* __restrict__ h0b) {
    int t = blockIdx.x * 256 + threadIdx.x;
    int n = t >> 4;
    int sub = t & 15;
    if (n >= MP) return;
    union { ushort4 u; __hip_bfloat16 h[4]; } o;
    if (n >= NN) {
        o.u = make_ushort4(0, 0, 0, 0);
        *(ushort4*)&h0b[(long long)n * NF + sub * 4] = o.u;
        return;
    }
    float4 acc = *(const float4*)&x[(long long)n * NF + sub * 4];
    int e0 = rowptr[n], e1 = rowptr[n + 1];
    for (int e = e0; e < e1; ++e) {
        int s = csr[e];
        float4 v = *(const float4*)&x[(long long)s * NF + sub * 4];
        acc.x += v.x; acc.y += v.y; acc.z += v.z; acc.w += v.w;
    }
    o.h[0] = __float2bfloat16(acc.x);
    o.h[1] = __float2bfloat16(acc.y);
    o.h[2] = __float2bfloat16(acc.z);
    o.h[3] = __float2bfloat16(acc.w);
    *(ushort4*)&h0b[(long long)n * NF + sub * 4] = o.u;
}

// W [K][N] fp32 -> WT [N][K] bf16
__global__ __launch_bounds__(256) void cvt_wt(const float* __restrict__ W,
                                              __hip_bfloat16* __restrict__ WT,
                                              int K, int N) {
    int t = blockIdx.x * 256 + threadIdx.x;
    if (t >= K * N) return;
    int n = t % N, k = t / N;
    WT[n * K + k] = __float2bfloat16(W[t]);
}

// ---------------------------------------------------------------------------
// FUSED GEMM1+GEMM2. Per block (mb, nb):
//  prologue: stage h0 tile (128x64) + W2T tile (kb=0) into LDS.
//  per K-step kb: (a) mini-gemm computes h1 slab [128 x 64] =
//      relu(h0 @ W1[:,kb:kb+64] + b1) into swizzled LDS (W1 frags direct from
//      L1-hot w1t); this compute overlaps the in-flight W2T stage DMA;
//      (b) barrier (drains stage), main gemm: af from H1s, bfr from Bs,
//      32 MFMA; (c) barrier, issue W2T stage for kb+1.
//  epilogue: bias + bf16 C-write + fused per-column BN statistics.
// h1 never touches HBM. Numerics identical to the split version (h1 rounds
// through bf16, same 2-chain MFMA K-order).
__global__ __launch_bounds__(256) void gemm12(const __hip_bfloat16* __restrict__ H0,
                                              const __hip_bfloat16* __restrict__ W1T,
                                              const float* __restrict__ b1,
                                              const __hip_bfloat16* __restrict__ W2T,
                                              const float* __restrict__ b2,
                                              __hip_bfloat16* __restrict__ C,
                                              float* __restrict__ partial) {
    __shared__ __align__(16) char smem[49152];
    __hip_bfloat16* H0s = (__hip_bfloat16*)smem;            // [128][64] swz
    __hip_bfloat16* H1s = (__hip_bfloat16*)(smem + 16384);  // [128][64] swz
    __hip_bfloat16* Bs  = (__hip_bfloat16*)(smem + 32768);  // [128][64] swz
    float* smsum = (float*)(smem + 32768);                  // alias Bs (epilogue)
    float* smsq  = (float*)(smem + 32768 + 2048);

    const int orig = blockIdx.x;
    const int L = (orig & 7) * CPX + (orig >> 3);
    const int mb = L >> 2, nb = L & 3;

    const int tid = threadIdx.x;
    const int lane = tid & 63;
    const int w = tid >> 6;
    const int wm = w >> 1, wn = w & 1;
    const long long rbase = (long long)mb * 128;
    const int nbase = nb * 128;
    const int r8  = lane >> 3;            // stage row within 8-row group
    const int swc = (lane & 7) ^ r8;      // pre-swizzled global chunk (rule #21)
    const int key = lane & 7;             // read swizzle key for rows ..+lo
    const int lo = lane & 15, hi = lane >> 4;

    // prologue: stage h0 tile + B tile (kb=0)
    {
        const __hip_bfloat16* ga = H0 + (rbase + w * 32 + r8) * NF + swc * 8;
        const __hip_bfloat16* gb =
            W2T + (long long)(nbase + w * 32 + r8) * NH + swc * 8;
        __hip_bfloat16* la = H0s + (w * 32) * 64;
        __hip_bfloat16* lb = Bs + (w * 32) * 64;
#pragma unroll
        for (int t = 0; t < 4; ++t) {
            GLOAD16(ga + t * 8 * NF, la + t * 8 * 64);
            GLOAD16(gb + (long long)t * 8 * NH, lb + t * 8 * 64);
        }
    }
    __syncthreads();

    f32x4 acc[4][4];
#pragma unroll
    for (int i = 0; i < 4; ++i)
#pragma unroll
        for (int j = 0; j < 4; ++j) acc[i][j] = (f32x4){0.f, 0.f, 0.f, 0.f};

    for (int kb8 = 0; kb8 < 8; ++kb8) {
        const int kb = kb8 * 64;

        // ---- mini-gemm: H1s[*][0..63] = relu(h0 @ W1[:,kb..kb+63] + b1) ----
        // wave w owns rows w*32..w*32+31 (mi2 x 16)
        {
            bf16x8 a2k0[2], a2k1[2];
#pragma unroll
            for (int mi2 = 0; mi2 < 2; ++mi2) {
                const __hip_bfloat16* hr = H0s + (w * 32 + mi2 * 16 + lo) * 64;
                a2k0[mi2] = *(const bf16x8*)&hr[(hi ^ key) << 3];
                a2k1[mi2] = *(const bf16x8*)&hr[((4 + hi) ^ key) << 3];
            }
            f32x4 acc2[2][4];
            float b1v[4];
#pragma unroll
            for (int ni2 = 0; ni2 < 4; ++ni2) {
                b1v[ni2] = b1[kb + ni2 * 16 + lo];
                const __hip_bfloat16* wr = W1T + (kb + ni2 * 16 + lo) * NF;
                bf16x8 bk0 = *(const bf16x8*)&wr[hi * 8];
                bf16x8 bk1 = *(const bf16x8*)&wr[32 + hi * 8];
#pragma unroll
                for (int mi2 = 0; mi2 < 2; ++mi2) {
                    f32x4 t0 = __builtin_amdgcn_mfma_f32_16x16x32_bf16(
                        a2k0[mi2], bk0, (f32x4){0.f, 0.f, 0.f, 0.f}, 0, 0, 0);
                    acc2[mi2][ni2] = __builtin_amdgcn_mfma_f32_16x16x32_bf16(
                        a2k1[mi2], bk1, t0, 0, 0, 0);
                }
            }
            // write slab: row = w*32+mi2*16+hi*4+r, col j = ni2*16+lo, swizzled
#pragma unroll
            for (int mi2 = 0; mi2 < 2; ++mi2) {
#pragma unroll
                for (int r = 0; r < 4; ++r) {
                    int row = w * 32 + mi2 * 16 + hi * 4 + r;
                    int rk = row & 7;
                    __hip_bfloat16* hw = H1s + row * 64;
#pragma unroll
                    for (int ni2 = 0; ni2 < 4; ++ni2) {
                        int j = ni2 * 16 + lo;
                        float v = fmaxf(acc2[mi2][ni2][r] + b1v[ni2], 0.f);
                        hw[(j & 7) + ((((j >> 3) ^ rk)) << 3)] = __float2bfloat16(v);
                    }
                }
            }
        }
        __syncthreads();   // H1s ready; also drains this kb's Bs stage DMA

        // ---- main gemm step: acc += h1slab @ W2[kb:kb+64, cols] ----
#pragma unroll
        for (int ks = 0; ks < 2; ++ks) {
            bf16x8 af[4], bfr[4];
#pragma unroll
            for (int mi = 0; mi < 4; ++mi)
                af[mi] = *(const bf16x8*)&H1s[(wm * 64 + mi * 16 + lo) * 64 +
                                              (((ks * 4 + hi) ^ key) << 3)];
#pragma unroll
            for (int ni = 0; ni < 4; ++ni)
                bfr[ni] = *(const bf16x8*)&Bs[(wn * 64 + ni * 16 + lo) * 64 +
                                              (((ks * 4 + hi) ^ key) << 3)];
#pragma unroll
            for (int mi = 0; mi < 4; ++mi)
#pragma unroll
                for (int ni = 0; ni < 4; ++ni)
                    acc[mi][ni] = __builtin_amdgcn_mfma_f32_16x16x32_bf16(
                        af[mi], bfr[ni], acc[mi][ni], 0, 0, 0);
        }
        __syncthreads();   // all waves done with Bs -> safe to restage

        if (kb8 < 7) {     // issue next B tile; drains at next iter's barrier
            const __hip_bfloat16* gb =
                W2T + (long long)(nbase + w * 32 + r8) * NH + (kb + 64) + swc * 8;
            __hip_bfloat16* lb = Bs + (w * 32) * 64;
#pragma unroll
            for (int t = 0; t < 4; ++t)
                GLOAD16(gb + (long long)t * 8 * NH, lb + t * 8 * 64);
        }
    }

    // epilogue: C/D layout col=lane&15, row=hi*4+reg ; fused BN stats
    if (tid < 128) { smsum[tid] = 0.f; smsq[tid] = 0.f; }
    __syncthreads();
    const int col0 = nbase + wn * 64 + lo;
    const long long row00 = rbase + wm * 64 + hi * 4;
#pragma unroll
    for (int ni = 0; ni < 4; ++ni) {
        int col = col0 + ni * 16;
        float bv = b2[col];
        float s = 0.f, q = 0.f;
#pragma unroll
        for (int mi = 0; mi < 4; ++mi) {
            long long r0 = row00 + mi * 16;
#pragma unroll
            for (int r = 0; r < 4; ++r) {
                float v = acc[mi][ni][r] + bv;
                C[(r0 + r) * NH + col] = __float2bfloat16(v);
                if ((r0 + r) < NN) { s += v; q += v * v; }
            }
        }
        s += __shfl_xor(s, 16); s += __shfl_xor(s, 32);
        q += __shfl_xor(q, 16); q += __shfl_xor(q, 32);
        if (lane < 16) {
            atomicAdd(&smsum[wn * 64 + ni * 16 + lane], s);
            atomicAdd(&smsq[wn * 64 + ni * 16 + lane], q);
        }
    }
    __syncthreads();
    if (tid < 128) {
        partial[mb * 1024 + nbase + tid] = smsum[tid];
        partial[mb * 1024 + 512 + nbase + tid] = smsq[tid];
    }
}

// reduce per-block partials: stats[j] = sum_mb partial[mb*1024 + j], j<1024
__global__ __launch_bounds__(256) void stats_reduce(const float* __restrict__ partial,
                                                    float* __restrict__ stats) {
    int j = blockIdx.x * 256 + threadIdx.x;   // 0..1023
    float s = 0.f;
    for (int mb = 0; mb < MB; ++mb) s += partial[mb * 1024 + j];
    stats[j] = s;
}

// BN(train stats) + ReLU + classifier fused; bf16 h2, per-lane register params
__global__ __launch_bounds__(256) void bn_cls(const __hip_bfloat16* __restrict__ h2b,
                                              const float* __restrict__ stats,
                                              const float* __restrict__ gamma,
                                              const float* __restrict__ beta,
                                              const float* __restrict__ Wc,
                                              const float* __restrict__ bc,
                                              float* __restrict__ out) {
    int tid = threadIdx.x;
    int lane = tid & 63;
    int k0 = lane * 8;
    float sc[8], sh[8], w0[8], w1[8];
#pragma unroll
    for (int j = 0; j < 8; ++j) {
        int k = k0 + j;
        float mean = stats[k] * (1.0f / NN);
        float var = stats[512 + k] * (1.0f / NN) - mean * mean;
        float rs = rsqrtf(var + 1e-5f);
        float s = gamma[k] * rs;
        sc[j] = s;
        sh[j] = beta[k] - mean * s;
        w0[j] = Wc[2 * k];
        w1[j] = Wc[2 * k + 1];
    }
    float bc0 = bc[0], bc1 = bc[1];
    int wid = blockIdx.x * 4 + (tid >> 6);
    int nw = gridDim.x * 4;
    for (int row = wid; row < NN; row += nw) {
        bf16x8 v8 = *(const bf16x8*)&h2b[(long long)row * NH + k0];
        float a0 = 0.f, a1 = 0.f;
#pragma unroll
        for (int j = 0; j < 8; ++j) {
            float v = __bfloat162float(((const __hip_bfloat16*)&v8)[j]);
            float hn = fmaxf(fmaf(v, sc[j], sh[j]), 0.f);
            a0 = fmaf(hn, w0[j], a0);
            a1 = fmaf(hn, w1[j], a1);
        }
#pragma unroll
        for (int off = 32; off; off >>= 1) {
            a0 += __shfl_xor(a0, off);
            a1 += __shfl_xor(a1, off);
        }
        if (lane == 0) {
            out[(long long)row * 2 + 0] = a0 + bc0;
            out[(long long)row * 2 + 1] = a1 + bc1;
        }
    }
}

// ---------------------------------------------------------------------------
extern "C" void kernel_launch(void* const* d_in, const int* in_sizes, int n_in,
                              void* d_out, int out_size, void* d_ws, size_t ws_size,
                              hipStream_t stream) {
    const float* x     = (const float*)d_in[0];
    const void*  ei    = d_in[1];
    const float* W1    = (const float*)d_in[2];
    const float* b1    = (const float*)d_in[3];
    const float* W2    = (const float*)d_in[4];
    const float* b2    = (const float*)d_in[5];
    const float* gamma = (const float*)d_in[6];
    const float* beta  = (const float*)d_in[7];
    const float* Wc    = (const float*)d_in[8];
    const float* bc    = (const float*)d_in[9];
    float* out = (float*)d_out;

    // workspace carve-up (256B aligned)
    char* base = (char*)d_ws;
    size_t o = 0;
    auto alloc = [&](size_t bytes) {
        char* p = base + o;
        o = (o + bytes + 255) & ~(size_t)255;
        return p;
    };
    __hip_bfloat16* h0b     = (__hip_bfloat16*)alloc((size_t)MP * NF * 2);
    __hip_bfloat16* h2b     = (__hip_bfloat16*)alloc((size_t)MP * NH * 2);
    __hip_bfloat16* w1t     = (__hip_bfloat16*)alloc((size_t)NH * NF * 2);
    __hip_bfloat16* w2t     = (__hip_bfloat16*)alloc((size_t)NH * NH * 2);
    int*            deg     = (int*)alloc((size_t)NN * 4);
    int*            rowptr  = (int*)alloc((size_t)(NN + 1) * 4);
    int*            cursor  = (int*)alloc((size_t)NN * 4);
    int*            csr     = (int*)alloc((size_t)NE * 4);
    int*            bsum    = (int*)alloc((size_t)NB * 4);
    int*            boff    = (int*)alloc((size_t)NB * 4);
    float*          partial = (float*)alloc((size_t)MB * 1024 * 4);
    float*          stats   = (float*)alloc(1024 * 4);
    int*            flag    = (int*)alloc(256);

    hipMemsetAsync(deg, 0, (size_t)NN * 4, stream);
    detect_idx<<<1, 1, 0, stream>>>((const int*)ei, flag);

    // CSR build + gather
    edge_hist<<<(NE + 255) / 256, 256, 0, stream>>>(ei, flag, deg);
    scan_local<<<NB, 256, 0, stream>>>(deg, rowptr, bsum);
    scan_bsum<<<1, 256, 0, stream>>>(bsum, boff);
    scan_add<<<NB, 256, 0, stream>>>(rowptr, boff, cursor);
    edge_fill<<<(NE + 255) / 256, 256, 0, stream>>>(ei, flag, cursor, csr);
    gather<<<(MP * 16 + 255) / 256, 256, 0, stream>>>(x, rowptr, csr, h0b);

    cvt_wt<<<(NF * NH + 255) / 256, 256, 0, stream>>>(W1, w1t, NF, NH);
    cvt_wt<<<(NH * NH + 255) / 256, 256, 0, stream>>>(W2, w2t, NH, NH);

    // fused GEMM1+GEMM2 with BN-stats epilogue
    gemm12<<<GRID, 256, 0, stream>>>(h0b, w1t, b1, w2t, b2, h2b, partial);

    stats_reduce<<<4, 256, 0, stream>>>(partial, stats);
    bn_cls<<<512, 256, 0, stream>>>(h2b, stats, gamma, beta, Wc, bc, out);
}

// Round 10
// 266.745 us; speedup vs baseline: 1.0261x; 1.0261x over previous
//
#include <hip/hip_runtime.h>
#include <hip/hip_bf16.h>

#define NN 50000      // nodes
#define MP 50176      // padded nodes (392 * 128)
#define NF 64         // features
#define NH 512        // hidden
#define NE 800000     // edges
#define NB 196        // scan blocks = ceil(NN/256)
#define MB 392        // M blocks = MP/128
#define GRID (MB * 4) // 1568 = 8 * 196
#define CPX (GRID / 8)

typedef __attribute__((ext_vector_type(8))) short bf16x8;
typedef __attribute__((ext_vector_type(4))) float f32x4;

#define GLOAD16(g, l)                                                        \
    __builtin_amdgcn_global_load_lds(                                        \
        (const __attribute__((address_space(1))) unsigned int*)(g),          \
        (__attribute__((address_space(3))) unsigned int*)(l), 16, 0, 0)

// ---------------------------------------------------------------------------
// detect whether edge_index is int64 (high dwords all zero) or int32
__global__ void detect_idx(const int* __restrict__ ei, int* __restrict__ flag) {
    if (threadIdx.x == 0 && blockIdx.x == 0) {
        int any = 0;
        for (int i = 0; i < 32; ++i) any |= ei[2 * i + 1];
        *flag = (any == 0) ? 1 : 0;   // 1 => int64 layout
    }
}

// ---------------------------------------------------------------------------
// CSR build: histogram of dst
__global__ __launch_bounds__(256) void edge_hist(const void* __restrict__ eiv,
                                                 const int* __restrict__ flag,
                                                 int* __restrict__ deg) {
    int e = blockIdx.x * 256 + threadIdx.x;
    if (e >= NE) return;
    int dst = *flag ? (int)((const long long*)eiv)[NE + e]
                    : ((const int*)eiv)[NE + e];
    atomicAdd(&deg[dst], 1);
}

// parallel scan step 1: per-block exclusive prefix + block sums
__global__ __launch_bounds__(256) void scan_local(const int* __restrict__ deg,
                                                  int* __restrict__ rowptr,
                                                  int* __restrict__ bsum) {
    __shared__ int sm[256];
    int tid = threadIdx.x;
    int i = blockIdx.x * 256 + tid;
    int v = (i < NN) ? deg[i] : 0;
    sm[tid] = v;
    __syncthreads();
    int acc = v;
#pragma unroll
    for (int off = 1; off < 256; off <<= 1) {
        int t = (tid >= off) ? sm[tid - off] : 0;
        __syncthreads();
        acc += t;
        sm[tid] = acc;
        __syncthreads();
    }
    if (i < NN) rowptr[i] = acc - v;           // local exclusive
    if (tid == 255) bsum[blockIdx.x] = acc;    // block total
}

// parallel scan step 2: exclusive scan of the NB block sums (1 block)
__global__ __launch_bounds__(256) void scan_bsum(const int* __restrict__ bsum,
                                                 int* __restrict__ boff) {
    __shared__ int sm[256];
    int tid = threadIdx.x;
    int v = (tid < NB) ? bsum[tid] : 0;
    sm[tid] = v;
    __syncthreads();
    int acc = v;
#pragma unroll
    for (int off = 1; off < 256; off <<= 1) {
        int t = (tid >= off) ? sm[tid - off] : 0;
        __syncthreads();
        acc += t;
        sm[tid] = acc;
        __syncthreads();
    }
    if (tid < NB) boff[tid] = acc - v;         // exclusive
}

// parallel scan step 3: add block offsets, emit rowptr & cursor
__global__ __launch_bounds__(256) void scan_add(int* __restrict__ rowptr,
                                                const int* __restrict__ boff,
                                                int* __restrict__ cursor) {
    int i = blockIdx.x * 256 + threadIdx.x;
    if (i < NN) {
        int r = rowptr[i] + boff[blockIdx.x];
        rowptr[i] = r;
        cursor[i] = r;
    }
    if (i == 0) rowptr[NN] = NE;   // total is the edge count by construction
}

// scatter edge sources into CSR slots
__global__ __launch_bounds__(256) void edge_fill(const void* __restrict__ eiv,
                                                 const int* __restrict__ flag,
                                                 int* __restrict__ cursor,
                                                 int* __restrict__ csr) {
    int e = blockIdx.x * 256 + threadIdx.x;
    if (e >= NE) return;
    int src, dst;
    if (*flag) {
        const long long* ei = (const long long*)eiv;
        src = (int)ei[e];
        dst = (int)ei[NE + e];
    } else {
        const int* ei = (const int*)eiv;
        src = ei[e];
        dst = ei[NE + e];
    }
    int pos = atomicAdd(&cursor[dst], 1);
    csr[pos] = src;
}

// gather-sum, one WAVE per node (lane = feature). No degree divergence within
// a wave; 4-deep unrolled neighbor loop keeps 4 independent x-row loads in
// flight (old version had a serial csr->x dependent chain).
__global__ __launch_bounds__(256) void gather(const float* __restrict__ x,
                                              const int* __restrict__ rowptr,
                                              const int* __restrict__ csr,
                                              __hip_bfloat16* __restrict__ h0b) {
    int n = blockIdx.x * 4 + (threadIdx.x >> 6);   // node id
    int lane = threadIdx.x & 63;
    if (n >= MP) return;
    if (n >= NN) {
        h0b[(long long)n * NF + lane] = __float2bfloat16(0.f);
        return;
    }
    float acc = x[(long long)n * NF + lane];
    int e = rowptr[n], e1 = rowptr[n + 1];
    for (; e + 4 <= e1; e += 4) {
        int s0 = csr[e], s1 = csr[e + 1], s2 = csr[e + 2], s3 = csr[e + 3];
        float v0 = x[(long long)s0 * NF + lane];
        float v1 = x[(long long)s1 * NF + lane];
        float v2 = x[(long long)s2 * NF + lane];
        float v3 = x[(long long)s3 * NF + lane];
        acc += (v0 + v1) + (v2 + v3);
    }
    for (; e < e1; ++e) acc += x[(long long)csr[e] * NF + lane];
    h0b[(long long)n * NF + lane] = __float2bfloat16(acc);
}

// W [K][N] fp32 -> WT [N][K] bf16
__global__ __launch_bounds__(256) void cvt_wt(const float* __restrict__ W,
                                              __hip_bfloat16* __restrict__ WT,
                                              int K, int N) {
    int t = blockIdx.x * 256 + threadIdx.x;
    if (t >= K * N) return;
    int n = t % N, k = t / N;
    WT[n * K + k] = __float2bfloat16(W[t]);
}

// ---------------------------------------------------------------------------
// GEMM1 (K=64): fully direct — A and B fragments read straight from global.
// h0b is L2/L3-hot (12.8 MB), w1t is L1/L2-hot (64 KB). No LDS, no barriers.
__global__ __launch_bounds__(256) void gemm1_direct(const __hip_bfloat16* __restrict__ A,
                                                    const __hip_bfloat16* __restrict__ BT,
                                                    const float* __restrict__ bias,
                                                    __hip_bfloat16* __restrict__ C) {
    const int orig = blockIdx.x;
    const int L = (orig & 7) * CPX + (orig >> 3);
    const int mb = L >> 2, nb = L & 3;

    const int tid = threadIdx.x;
    const int lane = tid & 63;
    const int w = tid >> 6;
    const int wm = w >> 1, wn = w & 1;
    const long long rbase = (long long)mb * 128;
    const int nbase = nb * 128;
    const int lo = lane & 15, hi = lane >> 4;

    f32x4 acc[4][4];
#pragma unroll
    for (int i = 0; i < 4; ++i)
#pragma unroll
        for (int j = 0; j < 4; ++j) acc[i][j] = (f32x4){0.f, 0.f, 0.f, 0.f};

#pragma unroll
    for (int ks = 0; ks < 2; ++ks) {
        bf16x8 af[4], bfr[4];
#pragma unroll
        for (int mi = 0; mi < 4; ++mi)
            af[mi] = *(const bf16x8*)&A[(rbase + wm * 64 + mi * 16 + lo) * NF +
                                        ks * 32 + hi * 8];
#pragma unroll
        for (int ni = 0; ni < 4; ++ni)
            bfr[ni] = *(const bf16x8*)&BT[(long long)(nbase + wn * 64 + ni * 16 + lo) * NF +
                                          ks * 32 + hi * 8];
#pragma unroll
        for (int mi = 0; mi < 4; ++mi)
#pragma unroll
            for (int ni = 0; ni < 4; ++ni)
                acc[mi][ni] = __builtin_amdgcn_mfma_f32_16x16x32_bf16(
                    af[mi], bfr[ni], acc[mi][ni], 0, 0, 0);
    }

    const int col0 = nbase + wn * 64 + lo;
    const long long row00 = rbase + wm * 64 + hi * 4;
#pragma unroll
    for (int ni = 0; ni < 4; ++ni) {
        int col = col0 + ni * 16;
        float bv = bias[col];
#pragma unroll
        for (int mi = 0; mi < 4; ++mi) {
            long long r0 = row00 + mi * 16;
#pragma unroll
            for (int r = 0; r < 4; ++r) {
                float v = fmaxf(acc[mi][ni][r] + bv, 0.f);   // ReLU
                C[(r0 + r) * NH + col] = __float2bfloat16(v);
            }
        }
    }
}

// ---------------------------------------------------------------------------
// GEMM2 (K=512): 2-phase double-buffered A staging (gload_lds, XOR-swizzled,
// ONE barrier per K-step, next-tile DMA in flight during MFMA); B fragments
// direct from global (w2t 512 KB, L2-hot). Fused per-column BN statistics.
// NOTE: no min-waves launch_bounds arg — R8 showed (256,4) caps VGPR at 64
// and spills (+32 MB scratch writes).
__global__ __launch_bounds__(256) void gemm2_pipe(const __hip_bfloat16* __restrict__ A,
                                                  const __hip_bfloat16* __restrict__ BT,
                                                  const float* __restrict__ bias,
                                                  __hip_bfloat16* __restrict__ C,
                                                  float* __restrict__ partial) {
    constexpr int BK = 64;
    __shared__ __align__(16) char smem[32768];
    __hip_bfloat16* Abuf0 = (__hip_bfloat16*)smem;
    __hip_bfloat16* Abuf1 = (__hip_bfloat16*)(smem + 16384);
    float* smsum = (float*)smem;            // aliases Abuf0 (dead after K-loop)
    float* smsq  = (float*)(smem + 2048);

    const int orig = blockIdx.x;
    const int L = (orig & 7) * CPX + (orig >> 3);
    const int mb = L >> 2, nb = L & 3;

    const int tid = threadIdx.x;
    const int lane = tid & 63;
    const int w = tid >> 6;
    const int wm = w >> 1, wn = w & 1;
    const long long rbase = (long long)mb * 128;
    const int nbase = nb * 128;
    const int r8  = lane >> 3;            // stage row within 8-row group
    const int swc = (lane & 7) ^ r8;      // pre-swizzled global chunk (rule #21)
    const int key = lane & 7;             // read-side swizzle key
    const int lo = lane & 15, hi = lane >> 4;

    // per-wave stage base (A rows w*32 .. w*32+31)
    const __hip_bfloat16* gaBase =
        A + (rbase + w * 32 + r8) * (long long)NH + swc * 8;
    const int laOff = (w * 32) * BK;

    f32x4 acc[4][4];
#pragma unroll
    for (int i = 0; i < 4; ++i)
#pragma unroll
        for (int j = 0; j < 4; ++j) acc[i][j] = (f32x4){0.f, 0.f, 0.f, 0.f};

    // prologue: stage tile kb=0 into buf0
    {
        __hip_bfloat16* la = Abuf0 + laOff;
#pragma unroll
        for (int t = 0; t < 4; ++t)
            GLOAD16(gaBase + (long long)t * 8 * NH, la + t * 8 * BK);
    }
    __syncthreads();

    int cur = 0;
    for (int kb8 = 0; kb8 < 8; ++kb8) {
        const int kb = kb8 * BK;
        // stage next tile into the other buffer (in flight during MFMA below)
        if (kb8 < 7) {
            __hip_bfloat16* la = (cur ? Abuf0 : Abuf1) + laOff;
            const __hip_bfloat16* ga = gaBase + kb + BK;
#pragma unroll
            for (int t = 0; t < 4; ++t)
                GLOAD16(ga + (long long)t * 8 * NH, la + t * 8 * BK);
        }
        const __hip_bfloat16* Ascur = cur ? Abuf1 : Abuf0;
#pragma unroll
        for (int ks = 0; ks < 2; ++ks) {
            bf16x8 af[4], bfr[4];
#pragma unroll
            for (int ni = 0; ni < 4; ++ni)   // B direct from global (L2-hot)
                bfr[ni] = *(const bf16x8*)&BT[(long long)(nbase + wn * 64 + ni * 16 + lo) * NH +
                                              kb + ks * 32 + hi * 8];
#pragma unroll
            for (int mi = 0; mi < 4; ++mi)
                af[mi] = *(const bf16x8*)&Ascur[(wm * 64 + mi * 16 + lo) * BK +
                                                (((ks * 4 + hi) ^ key) * 8)];
#pragma unroll
            for (int mi = 0; mi < 4; ++mi)
#pragma unroll
                for (int ni = 0; ni < 4; ++ni)
                    acc[mi][ni] = __builtin_amdgcn_mfma_f32_16x16x32_bf16(
                        af[mi], bfr[ni], acc[mi][ni], 0, 0, 0);
        }
        __syncthreads();   // drains next-tile DMA + all waves done with Ascur
        cur ^= 1;
    }

    // epilogue: C/D layout col=lane&15, row=hi*4+reg ; fused BN stats
    if (tid < 128) { smsum[tid] = 0.f; smsq[tid] = 0.f; }
    __syncthreads();
    const int col0 = nbase + wn * 64 + lo;
    const long long row00 = rbase + wm * 64 + hi * 4;
#pragma unroll
    for (int ni = 0; ni < 4; ++ni) {
        int col = col0 + ni * 16;
        float bv = bias[col];
        float s = 0.f, q = 0.f;
#pragma unroll
        for (int mi = 0; mi < 4; ++mi) {
            long long r0 = row00 + mi * 16;
#pragma unroll
            for (int r = 0; r < 4; ++r) {
                float v = acc[mi][ni][r] + bv;
                C[(r0 + r) * NH + col] = __float2bfloat16(v);
                if ((r0 + r) < NN) { s += v; q += v * v; }
            }
        }
        s += __shfl_xor(s, 16); s += __shfl_xor(s, 32);
        q += __shfl_xor(q, 16); q += __shfl_xor(q, 32);
        if (lane < 16) {
            atomicAdd(&smsum[wn * 64 + ni * 16 + lane], s);
            atomicAdd(&smsq[wn * 64 + ni * 16 + lane], q);
        }
    }
    __syncthreads();
    if (tid < 128) {
        partial[mb * 1024 + nbase + tid] = smsum[tid];
        partial[mb * 1024 + 512 + nbase + tid] = smsq[tid];
    }
}

// reduce per-block partials: stats[j] = sum_mb partial[mb*1024 + j], j<1024
__global__ __launch_bounds__(256) void stats_reduce(const float* __restrict__ partial,
                                                    float* __restrict__ stats) {
    int j = blockIdx.x * 256 + threadIdx.x;   // 0..1023
    float s = 0.f;
    for (int mb = 0; mb < MB; ++mb) s += partial[mb * 1024 + j];
    stats[j] = s;
}

// BN(train stats) + ReLU + classifier fused; bf16 h2, per-lane register params
__global__ __launch_bounds__(256) void bn_cls(const __hip_bfloat16* __restrict__ h2b,
                                              const float* __restrict__ stats,
                                              const float* __restrict__ gamma,
                                              const float* __restrict__ beta,
                                              const float* __restrict__ Wc,
                                              const float* __restrict__ bc,
                                              float* __restrict__ out) {
    int tid = threadIdx.x;
    int lane = tid & 63;
    int k0 = lane * 8;
    float sc[8], sh[8], w0[8], w1[8];
#pragma unroll
    for (int j = 0; j < 8; ++j) {
        int k = k0 + j;
        float mean = stats[k] * (1.0f / NN);
        float var = stats[512 + k] * (1.0f / NN) - mean * mean;
        float rs = rsqrtf(var + 1e-5f);
        float s = gamma[k] * rs;
        sc[j] = s;
        sh[j] = beta[k] - mean * s;
        w0[j] = Wc[2 * k];
        w1[j] = Wc[2 * k + 1];
    }
    float bc0 = bc[0], bc1 = bc[1];
    int wid = blockIdx.x * 4 + (tid >> 6);
    int nw = gridDim.x * 4;
    for (int row = wid; row < NN; row += nw) {
        bf16x8 v8 = *(const bf16x8*)&h2b[(long long)row * NH + k0];
        float a0 = 0.f, a1 = 0.f;
#pragma unroll
        for (int j = 0; j < 8; ++j) {
            float v = __bfloat162float(((const __hip_bfloat16*)&v8)[j]);
            float hn = fmaxf(fmaf(v, sc[j], sh[j]), 0.f);
            a0 = fmaf(hn, w0[j], a0);
            a1 = fmaf(hn, w1[j], a1);
        }
#pragma unroll
        for (int off = 32; off; off >>= 1) {
            a0 += __shfl_xor(a0, off);
            a1 += __shfl_xor(a1, off);
        }
        if (lane == 0) {
            out[(long long)row * 2 + 0] = a0 + bc0;
            out[(long long)row * 2 + 1] = a1 + bc1;
        }
    }
}

// ---------------------------------------------------------------------------
extern "C" void kernel_launch(void* const* d_in, const int* in_sizes, int n_in,
                              void* d_out, int out_size, void* d_ws, size_t ws_size,
                              hipStream_t stream) {
    const float* x     = (const float*)d_in[0];
    const void*  ei    = d_in[1];
    const float* W1    = (const float*)d_in[2];
    const float* b1    = (const float*)d_in[3];
    const float* W2    = (const float*)d_in[4];
    const float* b2    = (const float*)d_in[5];
    const float* gamma = (const float*)d_in[6];
    const float* beta  = (const float*)d_in[7];
    const float* Wc    = (const float*)d_in[8];
    const float* bc    = (const float*)d_in[9];
    float* out = (float*)d_out;

    // workspace carve-up (256B aligned)
    char* base = (char*)d_ws;
    size_t o = 0;
    auto alloc = [&](size_t bytes) {
        char* p = base + o;
        o = (o + bytes + 255) & ~(size_t)255;
        return p;
    };
    __hip_bfloat16* h0b     = (__hip_bfloat16*)alloc((size_t)MP * NF * 2);
    __hip_bfloat16* h1b     = (__hip_bfloat16*)alloc((size_t)MP * NH * 2);
    __hip_bfloat16* h2b     = (__hip_bfloat16*)alloc((size_t)MP * NH * 2);
    __hip_bfloat16* w1t     = (__hip_bfloat16*)alloc((size_t)NH * NF * 2);
    __hip_bfloat16* w2t     = (__hip_bfloat16*)alloc((size_t)NH * NH * 2);
    int*            deg     = (int*)alloc((size_t)NN * 4);
    int*            rowptr  = (int*)alloc((size_t)(NN + 1) * 4);
    int*            cursor  = (int*)alloc((size_t)NN * 4);
    int*            csr     = (int*)alloc((size_t)NE * 4);
    int*            bsum    = (int*)alloc((size_t)NB * 4);
    int*            boff    = (int*)alloc((size_t)NB * 4);
    float*          partial = (float*)alloc((size_t)MB * 1024 * 4);
    float*          stats   = (float*)alloc(1024 * 4);
    int*            flag    = (int*)alloc(256);

    hipMemsetAsync(deg, 0, (size_t)NN * 4, stream);
    detect_idx<<<1, 1, 0, stream>>>((const int*)ei, flag);

    // CSR build + gather
    edge_hist<<<(NE + 255) / 256, 256, 0, stream>>>(ei, flag, deg);
    scan_local<<<NB, 256, 0, stream>>>(deg, rowptr, bsum);
    scan_bsum<<<1, 256, 0, stream>>>(bsum, boff);
    scan_add<<<NB, 256, 0, stream>>>(rowptr, boff, cursor);
    edge_fill<<<(NE + 255) / 256, 256, 0, stream>>>(ei, flag, cursor, csr);
    gather<<<MP / 4, 256, 0, stream>>>(x, rowptr, csr, h0b);

    cvt_wt<<<(NF * NH + 255) / 256, 256, 0, stream>>>(W1, w1t, NF, NH);
    cvt_wt<<<(NH * NH + 255) / 256, 256, 0, stream>>>(W2, w2t, NH, NH);

    gemm1_direct<<<GRID, 256, 0, stream>>>(h0b, w1t, b1, h1b);
    gemm2_pipe<<<GRID, 256, 0, stream>>>(h1b, w2t, b2, h2b, partial);

    stats_reduce<<<4, 256, 0, stream>>>(partial, stats);
    bn_cls<<<512, 256, 0, stream>>>(h2b, stats, gamma, beta, Wc, bc, out);
}

// Round 11
// 232.675 us; speedup vs baseline: 1.1764x; 1.1464x over previous
//
#include <hip/hip_runtime.h>
#include <hip/hip_bf16.h>

#define NN 50000      // nodes
#define MP 50176      // padded nodes (392 * 128)
#define NF 64         // features
#define NH 512        // hidden
#define NE 800000     // edges
#define NB 196        // scan blocks = ceil(NN/256)
#define MB 392        // M blocks = MP/128
#define GRID (MB * 4) // 1568 = 8 * 196
#define CPX (GRID / 8)

typedef __attribute__((ext_vector_type(8))) short bf16x8;
typedef __attribute__((ext_vector_type(4))) float f32x4;

#define GLOAD16(g, l)                                                        \
    __builtin_amdgcn_global_load_lds(                                        \
        (const __attribute__((address_space(1))) unsigned int*)(g),          \
        (__attribute__((address_space(3))) unsigned int*)(l), 16, 0, 0)

// ---------------------------------------------------------------------------
// detect whether edge_index is int64 (high dwords all zero) or int32
__global__ void detect_idx(const int* __restrict__ ei, int* __restrict__ flag) {
    if (threadIdx.x == 0 && blockIdx.x == 0) {
        int any = 0;
        for (int i = 0; i < 32; ++i) any |= ei[2 * i + 1];
        *flag = (any == 0) ? 1 : 0;   // 1 => int64 layout
    }
}

// ---------------------------------------------------------------------------
// CSR build: histogram of dst
__global__ __launch_bounds__(256) void edge_hist(const void* __restrict__ eiv,
                                                 const int* __restrict__ flag,
                                                 int* __restrict__ deg) {
    int e = blockIdx.x * 256 + threadIdx.x;
    if (e >= NE) return;
    int dst = *flag ? (int)((const long long*)eiv)[NE + e]
                    : ((const int*)eiv)[NE + e];
    atomicAdd(&deg[dst], 1);
}

// parallel scan step 1: per-block exclusive prefix + block sums
__global__ __launch_bounds__(256) void scan_local(const int* __restrict__ deg,
                                                  int* __restrict__ rowptr,
                                                  int* __restrict__ bsum) {
    __shared__ int sm[256];
    int tid = threadIdx.x;
    int i = blockIdx.x * 256 + tid;
    int v = (i < NN) ? deg[i] : 0;
    sm[tid] = v;
    __syncthreads();
    int acc = v;
#pragma unroll
    for (int off = 1; off < 256; off <<= 1) {
        int t = (tid >= off) ? sm[tid - off] : 0;
        __syncthreads();
        acc += t;
        sm[tid] = acc;
        __syncthreads();
    }
    if (i < NN) rowptr[i] = acc - v;           // local exclusive
    if (tid == 255) bsum[blockIdx.x] = acc;    // block total
}

// parallel scan step 2: exclusive scan of the NB block sums (1 block)
__global__ __launch_bounds__(256) void scan_bsum(const int* __restrict__ bsum,
                                                 int* __restrict__ boff) {
    __shared__ int sm[256];
    int tid = threadIdx.x;
    int v = (tid < NB) ? bsum[tid] : 0;
    sm[tid] = v;
    __syncthreads();
    int acc = v;
#pragma unroll
    for (int off = 1; off < 256; off <<= 1) {
        int t = (tid >= off) ? sm[tid - off] : 0;
        __syncthreads();
        acc += t;
        sm[tid] = acc;
        __syncthreads();
    }
    if (tid < NB) boff[tid] = acc - v;         // exclusive
}

// parallel scan step 3: add block offsets, emit rowptr & cursor
__global__ __launch_bounds__(256) void scan_add(int* __restrict__ rowptr,
                                                const int* __restrict__ boff,
                                                int* __restrict__ cursor) {
    int i = blockIdx.x * 256 + threadIdx.x;
    if (i < NN) {
        int r = rowptr[i] + boff[blockIdx.x];
        rowptr[i] = r;
        cursor[i] = r;
    }
    if (i == 0) rowptr[NN] = NE;   // total is the edge count by construction
}

// scatter edge sources into CSR slots
__global__ __launch_bounds__(256) void edge_fill(const void* __restrict__ eiv,
                                                 const int* __restrict__ flag,
                                                 int* __restrict__ cursor,
                                                 int* __restrict__ csr) {
    int e = blockIdx.x * 256 + threadIdx.x;
    if (e >= NE) return;
    int src, dst;
    if (*flag) {
        const long long* ei = (const long long*)eiv;
        src = (int)ei[e];
        dst = (int)ei[NE + e];
    } else {
        const int* ei = (const int*)eiv;
        src = ei[e];
        dst = ei[NE + e];
    }
    int pos = atomicAdd(&cursor[dst], 1);
    csr[pos] = src;
}

// gather-sum, one WAVE per node (lane = feature). No degree divergence within
// a wave; 4-deep unrolled neighbor loop keeps 4 independent x-row loads in
// flight.
__global__ __launch_bounds__(256) void gather(const float* __restrict__ x,
                                              const int* __restrict__ rowptr,
                                              const int* __restrict__ csr,
                                              __hip_bfloat16* __restrict__ h0b) {
    int n = blockIdx.x * 4 + (threadIdx.x >> 6);   // node id
    int lane = threadIdx.x & 63;
    if (n >= MP) return;
    if (n >= NN) {
        h0b[(long long)n * NF + lane] = __float2bfloat16(0.f);
        return;
    }
    float acc = x[(long long)n * NF + lane];
    int e = rowptr[n], e1 = rowptr[n + 1];
    for (; e + 4 <= e1; e += 4) {
        int s0 = csr[e], s1 = csr[e + 1], s2 = csr[e + 2], s3 = csr[e + 3];
        float v0 = x[(long long)s0 * NF + lane];
        float v1 = x[(long long)s1 * NF + lane];
        float v2 = x[(long long)s2 * NF + lane];
        float v3 = x[(long long)s3 * NF + lane];
        acc += (v0 + v1) + (v2 + v3);
    }
    for (; e < e1; ++e) acc += x[(long long)csr[e] * NF + lane];
    h0b[(long long)n * NF + lane] = __float2bfloat16(acc);
}

// W [K][N] fp32 -> WT [N][K] bf16
__global__ __launch_bounds__(256) void cvt_wt(const float* __restrict__ W,
                                              __hip_bfloat16* __restrict__ WT,
                                              int K, int N) {
    int t = blockIdx.x * 256 + threadIdx.x;
    if (t >= K * N) return;
    int n = t % N, k = t / N;
    WT[n * K + k] = __float2bfloat16(W[t]);
}

// ---------------------------------------------------------------------------
// GEMM1 (K=64): fully direct — A and B fragments read straight from global.
__global__ __launch_bounds__(256) void gemm1_direct(const __hip_bfloat16* __restrict__ A,
                                                    const __hip_bfloat16* __restrict__ BT,
                                                    const float* __restrict__ bias,
                                                    __hip_bfloat16* __restrict__ C) {
    const int orig = blockIdx.x;
    const int L = (orig & 7) * CPX + (orig >> 3);
    const int mb = L >> 2, nb = L & 3;

    const int tid = threadIdx.x;
    const int lane = tid & 63;
    const int w = tid >> 6;
    const int wm = w >> 1, wn = w & 1;
    const long long rbase = (long long)mb * 128;
    const int nbase = nb * 128;
    const int lo = lane & 15, hi = lane >> 4;

    f32x4 acc[4][4];
#pragma unroll
    for (int i = 0; i < 4; ++i)
#pragma unroll
        for (int j = 0; j < 4; ++j) acc[i][j] = (f32x4){0.f, 0.f, 0.f, 0.f};

#pragma unroll
    for (int ks = 0; ks < 2; ++ks) {
        bf16x8 af[4], bfr[4];
#pragma unroll
        for (int mi = 0; mi < 4; ++mi)
            af[mi] = *(const bf16x8*)&A[(rbase + wm * 64 + mi * 16 + lo) * NF +
                                        ks * 32 + hi * 8];
#pragma unroll
        for (int ni = 0; ni < 4; ++ni)
            bfr[ni] = *(const bf16x8*)&BT[(long long)(nbase + wn * 64 + ni * 16 + lo) * NF +
                                          ks * 32 + hi * 8];
#pragma unroll
        for (int mi = 0; mi < 4; ++mi)
#pragma unroll
            for (int ni = 0; ni < 4; ++ni)
                acc[mi][ni] = __builtin_amdgcn_mfma_f32_16x16x32_bf16(
                    af[mi], bfr[ni], acc[mi][ni], 0, 0, 0);
    }

    const int col0 = nbase + wn * 64 + lo;
    const long long row00 = rbase + wm * 64 + hi * 4;
#pragma unroll
    for (int ni = 0; ni < 4; ++ni) {
        int col = col0 + ni * 16;
        float bv = bias[col];
#pragma unroll
        for (int mi = 0; mi < 4; ++mi) {
            long long r0 = row00 + mi * 16;
#pragma unroll
            for (int r = 0; r < 4; ++r) {
                float v = fmaxf(acc[mi][ni][r] + bv, 0.f);   // ReLU
                C[(r0 + r) * NH + col] = __float2bfloat16(v);
            }
        }
    }
}

// ---------------------------------------------------------------------------
// GEMM2 (K=512): counted-vmcnt 2-deep pipeline (T3/T4 minimum form).
// Two full LDS buffer sets (A 16KB + B 16KB each, 64 KB total), both operands
// staged via global_load_lds with XOR-swizzle. Raw s_barrier + asm
// s_waitcnt vmcnt(8) — the wait covers only loads issued 2 iters ago, which
// landed under the previous iteration's MFMA. NO __syncthreads in the loop
// (it would emit vmcnt(0) and reinstate the drain). sched_barrier(0) fences
// stop hipcc hoisting ds_reads across the raw barrier (rule #18).
__global__ __launch_bounds__(256) void gemm2_db(const __hip_bfloat16* __restrict__ A,
                                                const __hip_bfloat16* __restrict__ BT,
                                                const float* __restrict__ bias,
                                                __hip_bfloat16* __restrict__ C,
                                                float* __restrict__ partial) {
    constexpr int BK = 64;
    __shared__ __align__(16) char smem[65536];   // 2 sets x (A 16KB | B 16KB)
    float* smsum = (float*)smem;                 // alias set0 (dead after loop)
    float* smsq  = (float*)(smem + 2048);

    const int orig = blockIdx.x;
    const int L = (orig & 7) * CPX + (orig >> 3);
    const int mb = L >> 2, nb = L & 3;

    const int tid = threadIdx.x;
    const int lane = tid & 63;
    const int w = tid >> 6;
    const int wm = w >> 1, wn = w & 1;
    const long long rbase = (long long)mb * 128;
    const int nbase = nb * 128;
    const int r8  = lane >> 3;            // stage row within 8-row group
    const int swc = (lane & 7) ^ r8;      // pre-swizzled global chunk (rule #21)
    const int key = lane & 7;             // read-side swizzle key
    const int lo = lane & 15, hi = lane >> 4;

    const __hip_bfloat16* gaBase =
        A + (rbase + w * 32 + r8) * (long long)NH + swc * 8;
    const __hip_bfloat16* gbBase =
        BT + (long long)(nbase + w * 32 + r8) * NH + swc * 8;
    const int laOff = (w * 32) * BK;

    // stage buffer set s for K-offset kb: 4 A-loads + 4 B-loads per wave
    auto STAGE = [&](int s, int kb) {
        __hip_bfloat16* la = (__hip_bfloat16*)(smem + s * 32768) + laOff;
        __hip_bfloat16* lb = (__hip_bfloat16*)(smem + s * 32768 + 16384) + laOff;
#pragma unroll
        for (int t = 0; t < 4; ++t)
            GLOAD16(gaBase + kb + (long long)t * 8 * NH, la + t * 8 * BK);
#pragma unroll
        for (int t = 0; t < 4; ++t)
            GLOAD16(gbBase + kb + (long long)t * 8 * NH, lb + t * 8 * BK);
    };

    f32x4 acc[4][4];
#pragma unroll
    for (int i = 0; i < 4; ++i)
#pragma unroll
        for (int j = 0; j < 4; ++j) acc[i][j] = (f32x4){0.f, 0.f, 0.f, 0.f};

    // prologue: 2-deep prefetch (16 loads outstanding per wave)
    STAGE(0, 0);
    STAGE(1, BK);

#pragma unroll
    for (int t = 0; t < 8; ++t) {
        // wait for buffer t&1's loads (oldest 8); the newer 8 stay in flight
        if (t == 7) { asm volatile("s_waitcnt vmcnt(0)" ::: "memory"); }
        else        { asm volatile("s_waitcnt vmcnt(8)" ::: "memory"); }
        __builtin_amdgcn_s_barrier();          // all waves' DMA for cur landed
        __builtin_amdgcn_sched_barrier(0);

        const __hip_bfloat16* Ac = (const __hip_bfloat16*)(smem + (t & 1) * 32768);
        const __hip_bfloat16* Bc = Ac + 8192;  // +16384 bytes
#pragma unroll
        for (int ks = 0; ks < 2; ++ks) {
            bf16x8 af[4], bfr[4];
#pragma unroll
            for (int mi = 0; mi < 4; ++mi)
                af[mi] = *(const bf16x8*)&Ac[(wm * 64 + mi * 16 + lo) * BK +
                                             (((ks * 4 + hi) ^ key) * 8)];
#pragma unroll
            for (int ni = 0; ni < 4; ++ni)
                bfr[ni] = *(const bf16x8*)&Bc[(wn * 64 + ni * 16 + lo) * BK +
                                              (((ks * 4 + hi) ^ key) * 8)];
#pragma unroll
            for (int mi = 0; mi < 4; ++mi)
#pragma unroll
                for (int ni = 0; ni < 4; ++ni)
                    acc[mi][ni] = __builtin_amdgcn_mfma_f32_16x16x32_bf16(
                        af[mi], bfr[ni], acc[mi][ni], 0, 0, 0);
        }
        __builtin_amdgcn_sched_barrier(0);
        __builtin_amdgcn_s_barrier();          // all waves done reading cur
        __builtin_amdgcn_sched_barrier(0);
        if (t < 6) STAGE(t & 1, (t + 2) * BK); // refill freed buffer, 2 ahead
    }

    // epilogue: vmcnt==0 here; full barrier before LDS alias reuse
    __syncthreads();
    if (tid < 128) { smsum[tid] = 0.f; smsq[tid] = 0.f; }
    __syncthreads();
    const int col0 = nbase + wn * 64 + lo;
    const long long row00 = rbase + wm * 64 + hi * 4;
#pragma unroll
    for (int ni = 0; ni < 4; ++ni) {
        int col = col0 + ni * 16;
        float bv = bias[col];
        float s = 0.f, q = 0.f;
#pragma unroll
        for (int mi = 0; mi < 4; ++mi) {
            long long r0 = row00 + mi * 16;
#pragma unroll
            for (int r = 0; r < 4; ++r) {
                float v = acc[mi][ni][r] + bv;
                C[(r0 + r) * NH + col] = __float2bfloat16(v);
                if ((r0 + r) < NN) { s += v; q += v * v; }
            }
        }
        s += __shfl_xor(s, 16); s += __shfl_xor(s, 32);
        q += __shfl_xor(q, 16); q += __shfl_xor(q, 32);
        if (lane < 16) {
            atomicAdd(&smsum[wn * 64 + ni * 16 + lane], s);
            atomicAdd(&smsq[wn * 64 + ni * 16 + lane], q);
        }
    }
    __syncthreads();
    if (tid < 128) {
        partial[mb * 1024 + nbase + tid] = smsum[tid];
        partial[mb * 1024 + 512 + nbase + tid] = smsq[tid];
    }
}

// reduce per-block partials: stats[j] = sum_mb partial[mb*1024 + j], j<1024
__global__ __launch_bounds__(256) void stats_reduce(const float* __restrict__ partial,
                                                    float* __restrict__ stats) {
    int j = blockIdx.x * 256 + threadIdx.x;   // 0..1023
    float s = 0.f;
    for (int mb = 0; mb < MB; ++mb) s += partial[mb * 1024 + j];
    stats[j] = s;
}

// BN(train stats) + ReLU + classifier fused; bf16 h2, per-lane register params
__global__ __launch_bounds__(256) void bn_cls(const __hip_bfloat16* __restrict__ h2b,
                                              const float* __restrict__ stats,
                                              const float* __restrict__ gamma,
                                              const float* __restrict__ beta,
                                              const float* __restrict__ Wc,
                                              const float* __restrict__ bc,
                                              float* __restrict__ out) {
    int tid = threadIdx.x;
    int lane = tid & 63;
    int k0 = lane * 8;
    float sc[8], sh[8], w0[8], w1[8];
#pragma unroll
    for (int j = 0; j < 8; ++j) {
        int k = k0 + j;
        float mean = stats[k] * (1.0f / NN);
        float var = stats[512 + k] * (1.0f / NN) - mean * mean;
        float rs = rsqrtf(var + 1e-5f);
        float s = gamma[k] * rs;
        sc[j] = s;
        sh[j] = beta[k] - mean * s;
        w0[j] = Wc[2 * k];
        w1[j] = Wc[2 * k + 1];
    }
    float bc0 = bc[0], bc1 = bc[1];
    int wid = blockIdx.x * 4 + (tid >> 6);
    int nw = gridDim.x * 4;
    for (int row = wid; row < NN; row += nw) {
        bf16x8 v8 = *(const bf16x8*)&h2b[(long long)row * NH + k0];
        float a0 = 0.f, a1 = 0.f;
#pragma unroll
        for (int j = 0; j < 8; ++j) {
            float v = __bfloat162float(((const __hip_bfloat16*)&v8)[j]);
            float hn = fmaxf(fmaf(v, sc[j], sh[j]), 0.f);
            a0 = fmaf(hn, w0[j], a0);
            a1 = fmaf(hn, w1[j], a1);
        }
#pragma unroll
        for (int off = 32; off; off >>= 1) {
            a0 += __shfl_xor(a0, off);
            a1 += __shfl_xor(a1, off);
        }
        if (lane == 0) {
            out[(long long)row * 2 + 0] = a0 + bc0;
            out[(long long)row * 2 + 1] = a1 + bc1;
        }
    }
}

// ---------------------------------------------------------------------------
extern "C" void kernel_launch(void* const* d_in, const int* in_sizes, int n_in,
                              void* d_out, int out_size, void* d_ws, size_t ws_size,
                              hipStream_t stream) {
    const float* x     = (const float*)d_in[0];
    const void*  ei    = d_in[1];
    const float* W1    = (const float*)d_in[2];
    const float* b1    = (const float*)d_in[3];
    const float* W2    = (const float*)d_in[4];
    const float* b2    = (const float*)d_in[5];
    const float* gamma = (const float*)d_in[6];
    const float* beta  = (const float*)d_in[7];
    const float* Wc    = (const float*)d_in[8];
    const float* bc    = (const float*)d_in[9];
    float* out = (float*)d_out;

    // workspace carve-up (256B aligned)
    char* base = (char*)d_ws;
    size_t o = 0;
    auto alloc = [&](size_t bytes) {
        char* p = base + o;
        o = (o + bytes + 255) & ~(size_t)255;
        return p;
    };
    __hip_bfloat16* h0b     = (__hip_bfloat16*)alloc((size_t)MP * NF * 2);
    __hip_bfloat16* h1b     = (__hip_bfloat16*)alloc((size_t)MP * NH * 2);
    __hip_bfloat16* h2b     = (__hip_bfloat16*)alloc((size_t)MP * NH * 2);
    __hip_bfloat16* w1t     = (__hip_bfloat16*)alloc((size_t)NH * NF * 2);
    __hip_bfloat16* w2t     = (__hip_bfloat16*)alloc((size_t)NH * NH * 2);
    int*            deg     = (int*)alloc((size_t)NN * 4);
    int*            rowptr  = (int*)alloc((size_t)(NN + 1) * 4);
    int*            cursor  = (int*)alloc((size_t)NN * 4);
    int*            csr     = (int*)alloc((size_t)NE * 4);
    int*            bsum    = (int*)alloc((size_t)NB * 4);
    int*            boff    = (int*)alloc((size_t)NB * 4);
    float*          partial = (float*)alloc((size_t)MB * 1024 * 4);
    float*          stats   = (float*)alloc(1024 * 4);
    int*            flag    = (int*)alloc(256);

    hipMemsetAsync(deg, 0, (size_t)NN * 4, stream);
    detect_idx<<<1, 1, 0, stream>>>((const int*)ei, flag);

    // CSR build + gather
    edge_hist<<<(NE + 255) / 256, 256, 0, stream>>>(ei, flag, deg);
    scan_local<<<NB, 256, 0, stream>>>(deg, rowptr, bsum);
    scan_bsum<<<1, 256, 0, stream>>>(bsum, boff);
    scan_add<<<NB, 256, 0, stream>>>(rowptr, boff, cursor);
    edge_fill<<<(NE + 255) / 256, 256, 0, stream>>>(ei, flag, cursor, csr);
    gather<<<MP / 4, 256, 0, stream>>>(x, rowptr, csr, h0b);

    cvt_wt<<<(NF * NH + 255) / 256, 256, 0, stream>>>(W1, w1t, NF, NH);
    cvt_wt<<<(NH * NH + 255) / 256, 256, 0, stream>>>(W2, w2t, NH, NH);

    gemm1_direct<<<GRID, 256, 0, stream>>>(h0b, w1t, b1, h1b);
    gemm2_db<<<GRID, 256, 0, stream>>>(h1b, w2t, b2, h2b, partial);

    stats_reduce<<<4, 256, 0, stream>>>(partial, stats);
    bn_cls<<<512, 256, 0, stream>>>(h2b, stats, gamma, beta, Wc, bc, out);
}